// Round 1
// baseline (568.643 us; speedup 1.0000x reference)
//
#include <hip/hip_runtime.h>

#define D_ 128
#define N_ 2048
#define BH_ 128

typedef __attribute__((ext_vector_type(8))) short short8;
typedef __attribute__((ext_vector_type(4))) float f32x4;

#define MFMA_BF16(a, b, c) __builtin_amdgcn_mfma_f32_16x16x32_bf16((a), (b), (c), 0, 0, 0)

static __device__ __forceinline__ unsigned short f2bf(float x) {
    unsigned int u = __builtin_bit_cast(unsigned int, x);
    u += 0x7fffu + ((u >> 16) & 1u);          // round-to-nearest-even
    return (unsigned short)(u >> 16);
}
static __device__ __forceinline__ float bf2f(unsigned short h) {
    unsigned int u = ((unsigned int)h) << 16;
    return __builtin_bit_cast(float, u);
}
// split fp32 -> bf16 hi + bf16 lo (captures ~16 mantissa bits total)
static __device__ __forceinline__ void split8(const float* x, short8* hi, short8* lo) {
    short8 h, l;
#pragma unroll
    for (int i = 0; i < 8; ++i) {
        unsigned short hh = f2bf(x[i]);
        h[i] = (short)hh;
        l[i] = (short)f2bf(x[i] - bf2f(hh));
    }
    *hi = h; *lo = l;
}
static __device__ __forceinline__ short8 ones_frag() {
    short8 o;
#pragma unroll
    for (int i = 0; i < 8; ++i) o[i] = (short)0x3F80;  // bf16(1.0)
    return o;
}

// ---------------------------------------------------------------------------
// Kernel 1: per (head, n-split): E = exp(a@k) (no max subtraction; fp32/bf16
// exponent range is sufficient), accumulate accT[vd][t] += (E@v)^T and
// lsum[t] += rowsum(bf16(E)) via ones-MFMA (consistent normalization).
// S2 computed TRANSPOSED (M-dim = keys m) so exp results pack as b64 into
// the [t][m] E-buffer used as MFMA A-fragments.
// ---------------------------------------------------------------------------
__global__ __launch_bounds__(256, 2) void k1_agg(
    const float* __restrict__ Ag, const float* __restrict__ Kg,
    const float* __restrict__ Vg, float* __restrict__ accT,
    float* __restrict__ lsum)
{
    const int head  = blockIdx.x >> 2;
    const int split = blockIdx.x & 3;
    const float* ah = Ag + (size_t)head * (D_ * D_);
    const float* kh = Kg + (size_t)head * (D_ * N_);
    const float* vh = Vg + (size_t)head * (N_ * D_);
    float* accTh = accT + (size_t)head * (D_ * D_);
    float* lh    = lsum + head * D_;

    const int tid  = threadIdx.x;
    const int lane = tid & 63;
    const int w    = tid >> 6;   // wave id, owns agent rows [w*32, w*32+32)
    const int l15  = lane & 15;
    const int qd   = lane >> 4;

    __shared__ __align__(16) short kt_hi[32][136];  // k^T chunk [m][j], j-contig
    __shared__ __align__(16) short kt_lo[32][136];
    __shared__ __align__(16) short vt[128][40];     // v^T chunk [vd][m], m-contig
    __shared__ __align__(16) short eb[4][32][40];   // per-wave E [t][m], m-contig

    // Preload a-fragments (B operand of S2^T): B[k=j][n=t] = a[t][j], row-major.
    short8 aBh[2][4], aBl[2][4];
#pragma unroll
    for (int nt = 0; nt < 2; ++nt) {
        const int t = w * 32 + nt * 16 + l15;
#pragma unroll
        for (int kt = 0; kt < 4; ++kt) {
            float x[8];
            const float* p = ah + t * D_ + kt * 32 + qd * 8;
            *(f32x4*)&x[0] = *(const f32x4*)p;
            *(f32x4*)&x[4] = *(const f32x4*)(p + 4);
            split8(x, &aBh[nt][kt], &aBl[nt][kt]);
        }
    }

    f32x4 agg[2][8];
    f32x4 lac[2];
#pragma unroll
    for (int tt = 0; tt < 2; ++tt) {
        f32x4 z = {0.f, 0.f, 0.f, 0.f};
        lac[tt] = z;
#pragma unroll
        for (int nt = 0; nt < 8; ++nt) agg[tt][nt] = z;
    }
    const short8 ones = ones_frag();

    for (int c = 0; c < 16; ++c) {
        const int m0 = split * 512 + c * 32;
        __syncthreads();
        {   // stage K^T hi/lo: thread owns 2 m-rows x 8 j
            const int ml = (tid & 15) * 2;
            const int j0 = (tid >> 4) * 8;
            float xa[8], xb[8];
#pragma unroll
            for (int jj = 0; jj < 8; ++jj) {
                const float2 x = *(const float2*)(kh + (size_t)(j0 + jj) * N_ + m0 + ml);
                xa[jj] = x.x; xb[jj] = x.y;
            }
            short8 h, l;
            split8(xa, &h, &l);
            *(short8*)&kt_hi[ml][j0] = h;
            *(short8*)&kt_lo[ml][j0] = l;
            split8(xb, &h, &l);
            *(short8*)&kt_hi[ml + 1][j0] = h;
            *(short8*)&kt_lo[ml + 1][j0] = l;
        }
        {   // stage V^T bf16: thread owns 2 vd-rows x 8 m
            const int vp  = (tid & 63) * 2;
            const int ml2 = (tid >> 6) * 8;
            short8 va, vb;
#pragma unroll
            for (int mm = 0; mm < 8; ++mm) {
                const float2 x = *(const float2*)(vh + (size_t)(m0 + ml2 + mm) * D_ + vp);
                va[mm] = (short)f2bf(x.x);
                vb[mm] = (short)f2bf(x.y);
            }
            *(short8*)&vt[vp][ml2]     = va;
            *(short8*)&vt[vp + 1][ml2] = vb;
        }
        __syncthreads();

        // S2^T: D[m][t] = sum_j k[j][m] * a[t][j]  (3-term bf16 split)
        f32x4 s[2][2];
        {
            f32x4 z = {0.f, 0.f, 0.f, 0.f};
            s[0][0] = z; s[0][1] = z; s[1][0] = z; s[1][1] = z;
        }
#pragma unroll
        for (int kt = 0; kt < 4; ++kt) {
            short8 Ah[2], Al[2];
#pragma unroll
            for (int mt = 0; mt < 2; ++mt) {
                Ah[mt] = *(const short8*)&kt_hi[mt * 16 + l15][kt * 32 + qd * 8];
                Al[mt] = *(const short8*)&kt_lo[mt * 16 + l15][kt * 32 + qd * 8];
            }
#pragma unroll
            for (int mt = 0; mt < 2; ++mt)
#pragma unroll
            for (int nt = 0; nt < 2; ++nt) {
                s[mt][nt] = MFMA_BF16(Ah[mt], aBh[nt][kt], s[mt][nt]);
                s[mt][nt] = MFMA_BF16(Ah[mt], aBl[nt][kt], s[mt][nt]);
                s[mt][nt] = MFMA_BF16(Al[mt], aBh[nt][kt], s[mt][nt]);
            }
        }
        // exp (no max subtraction) -> bf16 -> packed b64 into eb[t][m]
#pragma unroll
        for (int mt = 0; mt < 2; ++mt)
#pragma unroll
        for (int nt = 0; nt < 2; ++nt) {
            const unsigned int e0 = f2bf(__expf(s[mt][nt][0]));
            const unsigned int e1 = f2bf(__expf(s[mt][nt][1]));
            const unsigned int e2 = f2bf(__expf(s[mt][nt][2]));
            const unsigned int e3 = f2bf(__expf(s[mt][nt][3]));
            const unsigned long long pk =
                (unsigned long long)(e0 | (e1 << 16)) |
                ((unsigned long long)(e2 | (e3 << 16)) << 32);
            *(unsigned long long*)&eb[w][nt * 16 + l15][mt * 16 + qd * 4] = pk;
        }
        // PV: agg[t][vd] += E[t][m] * v^T, plus ones-MFMA row sums
        short8 Ef[2];
#pragma unroll
        for (int tt = 0; tt < 2; ++tt)
            Ef[tt] = *(const short8*)&eb[w][tt * 16 + l15][qd * 8];
#pragma unroll
        for (int nt = 0; nt < 8; ++nt) {
            const short8 Bv = *(const short8*)&vt[nt * 16 + l15][qd * 8];
            agg[0][nt] = MFMA_BF16(Ef[0], Bv, agg[0][nt]);
            agg[1][nt] = MFMA_BF16(Ef[1], Bv, agg[1][nt]);
        }
        lac[0] = MFMA_BF16(Ef[0], ones, lac[0]);
        lac[1] = MFMA_BF16(Ef[1], ones, lac[1]);
    }

    // epilogue: atomic accumulate partials into accT[vd][t] and lsum[t]
#pragma unroll
    for (int tt = 0; tt < 2; ++tt) {
        const int t = w * 32 + tt * 16 + qd * 4;
#pragma unroll
        for (int nt = 0; nt < 8; ++nt) {
            const int vd = nt * 16 + l15;
#pragma unroll
            for (int r = 0; r < 4; ++r)
                atomicAdd(&accTh[vd * D_ + t + r], agg[tt][nt][r]);
        }
        if (l15 == 0) {
#pragma unroll
            for (int r = 0; r < 4; ++r)
                atomicAdd(&lh[t + r], lac[tt][r]);
        }
    }
}

// ---------------------------------------------------------------------------
// Kernel 2: per (head, 128-row tile): s1^T[j][n] = sum_i a[i][j] q[n][i]
// (3-term split, a^T staged in K-quarter phases), column softmax (2 shuffles),
// P packs b64 into [n][t] (exactly the PV B-fragment layout), then
// out^T[vd][n] = sum_t agg^T[vd][t] P^T[t][n], l1 via ones-MFMA, coalesced
// float4 stores.
// ---------------------------------------------------------------------------
__global__ __launch_bounds__(256, 2) void k2_out(
    const float* __restrict__ Qg, const float* __restrict__ Ag,
    const float* __restrict__ accT, const float* __restrict__ lsum,
    float* __restrict__ outg)
{
    const int head = blockIdx.x >> 4;
    const int nb   = blockIdx.x & 15;
    const int n0   = nb * 128;
    const float* qh    = Qg + (size_t)head * (N_ * D_);
    const float* ahg   = Ag + (size_t)head * (D_ * D_);
    const float* accTh = accT + (size_t)head * (D_ * D_);
    const float* lh    = lsum + head * D_;
    float* oh = outg + (size_t)head * (N_ * D_);

    const int tid  = threadIdx.x;
    const int lane = tid & 63;
    const int w    = tid >> 6;   // wave owns n-rows [w*32, w*32+32)
    const int l15  = lane & 15;
    const int qd   = lane >> 4;

    __shared__ __align__(16) char smem_raw[65536];
    short (*qhi)[40]   = (short(*)[40])(smem_raw);           // q hi quarter [n][i]
    short (*qlo)[40]   = (short(*)[40])(smem_raw + 10240);   // q lo quarter
    short (*aTq)[40]   = (short(*)[40])(smem_raw + 20480);   // a^T quarter [j][i]
    short (*Pbuf)[136] = (short(*)[136])(smem_raw + 30720);  // P [n][t]
    short (*agq)[40]   = (short(*)[40])(smem_raw);           // agg^T quarter (PV reuse)

    const short8 ones = ones_frag();

    f32x4 sA[8][2];
    {
        f32x4 z = {0.f, 0.f, 0.f, 0.f};
#pragma unroll
        for (int mt = 0; mt < 8; ++mt) { sA[mt][0] = z; sA[mt][1] = z; }
    }

    for (int kq = 0; kq < 4; ++kq) {
        __syncthreads();
        {   // stage q quarter hi+lo: thread owns 1 n-row x 16 i
            const int n = tid & 127, ih = (tid >> 7) * 16;
            const float* p = qh + (size_t)(n0 + n) * D_ + kq * 32 + ih;
#pragma unroll
            for (int g = 0; g < 2; ++g) {
                float x[8];
                *(f32x4*)&x[0] = *(const f32x4*)(p + g * 8);
                *(f32x4*)&x[4] = *(const f32x4*)(p + g * 8 + 4);
                short8 h, l;
                split8(x, &h, &l);
                *(short8*)&qhi[n][ih + g * 8] = h;
                *(short8*)&qlo[n][ih + g * 8] = l;
            }
        }
        {   // stage a^T hi quarter: thread owns 2 j x 8 i (transposing read)
            const int jp = (tid & 63) * 2, i0l = (tid >> 6) * 8;
            short8 ha, hb;
#pragma unroll
            for (int ii = 0; ii < 8; ++ii) {
                const float2 x = *(const float2*)(ahg + (size_t)(kq * 32 + i0l + ii) * D_ + jp);
                ha[ii] = (short)f2bf(x.x);
                hb[ii] = (short)f2bf(x.y);
            }
            *(short8*)&aTq[jp][i0l]     = ha;
            *(short8*)&aTq[jp + 1][i0l] = hb;
        }
        __syncthreads();
        {   // hi terms: aT_hi*q_hi + aT_hi*q_lo
            short8 Bh[2], Bl[2];
#pragma unroll
            for (int nt = 0; nt < 2; ++nt) {
                Bh[nt] = *(const short8*)&qhi[w * 32 + nt * 16 + l15][qd * 8];
                Bl[nt] = *(const short8*)&qlo[w * 32 + nt * 16 + l15][qd * 8];
            }
#pragma unroll
            for (int mt = 0; mt < 8; ++mt) {
                const short8 Af = *(const short8*)&aTq[mt * 16 + l15][qd * 8];
#pragma unroll
                for (int nt = 0; nt < 2; ++nt) {
                    sA[mt][nt] = MFMA_BF16(Af, Bh[nt], sA[mt][nt]);
                    sA[mt][nt] = MFMA_BF16(Af, Bl[nt], sA[mt][nt]);
                }
            }
        }
        __syncthreads();
        {   // stage a^T lo quarter (overwrite)
            const int jp = (tid & 63) * 2, i0l = (tid >> 6) * 8;
            short8 la, lb;
#pragma unroll
            for (int ii = 0; ii < 8; ++ii) {
                const float2 x = *(const float2*)(ahg + (size_t)(kq * 32 + i0l + ii) * D_ + jp);
                unsigned short h0 = f2bf(x.x), h1 = f2bf(x.y);
                la[ii] = (short)f2bf(x.x - bf2f(h0));
                lb[ii] = (short)f2bf(x.y - bf2f(h1));
            }
            *(short8*)&aTq[jp][i0l]     = la;
            *(short8*)&aTq[jp + 1][i0l] = lb;
        }
        __syncthreads();
        {   // lo term: aT_lo*q_hi
            short8 Bh[2];
#pragma unroll
            for (int nt = 0; nt < 2; ++nt)
                Bh[nt] = *(const short8*)&qhi[w * 32 + nt * 16 + l15][qd * 8];
#pragma unroll
            for (int mt = 0; mt < 8; ++mt) {
                const short8 Af = *(const short8*)&aTq[mt * 16 + l15][qd * 8];
#pragma unroll
                for (int nt = 0; nt < 2; ++nt)
                    sA[mt][nt] = MFMA_BF16(Af, Bh[nt], sA[mt][nt]);
            }
        }
    }

    // column softmax over t (rows of s1^T): local max + 2 xor-shuffles
#pragma unroll
    for (int nt = 0; nt < 2; ++nt) {
        float mx = -1e30f;
#pragma unroll
        for (int mt = 0; mt < 8; ++mt)
#pragma unroll
            for (int r = 0; r < 4; ++r) mx = fmaxf(mx, sA[mt][nt][r]);
        mx = fmaxf(mx, __shfl_xor(mx, 16));
        mx = fmaxf(mx, __shfl_xor(mx, 32));
        const int n = w * 32 + nt * 16 + l15;
#pragma unroll
        for (int mt = 0; mt < 8; ++mt) {
            const unsigned int e0 = f2bf(__expf(sA[mt][nt][0] - mx));
            const unsigned int e1 = f2bf(__expf(sA[mt][nt][1] - mx));
            const unsigned int e2 = f2bf(__expf(sA[mt][nt][2] - mx));
            const unsigned int e3 = f2bf(__expf(sA[mt][nt][3] - mx));
            const unsigned long long pk =
                (unsigned long long)(e0 | (e1 << 16)) |
                ((unsigned long long)(e2 | (e3 << 16)) << 32);
            *(unsigned long long*)&Pbuf[n][mt * 16 + qd * 4] = pk;
        }
    }

    // PV: out^T[vd][n] = sum_t agg^T[vd][t] * P^T[t][n]; l1 via ones-MFMA
    f32x4 oA[8][2];
    f32x4 l1A[2];
    {
        f32x4 z = {0.f, 0.f, 0.f, 0.f};
#pragma unroll
        for (int mt = 0; mt < 8; ++mt) { oA[mt][0] = z; oA[mt][1] = z; }
        l1A[0] = z; l1A[1] = z;
    }
    for (int tq = 0; tq < 4; ++tq) {
        __syncthreads();
        {   // stage agg^T quarter = accT/lsum (thread: 1 vd x 16 t)
            const int vd = tid & 127, th = (tid >> 7) * 16;
            const int t0 = tq * 32 + th;
            float acc[16], ls[16];
#pragma unroll
            for (int g = 0; g < 4; ++g) {
                *(f32x4*)&acc[g * 4] = *(const f32x4*)(accTh + vd * D_ + t0 + g * 4);
                *(f32x4*)&ls[g * 4]  = *(const f32x4*)(lh + t0 + g * 4);
            }
#pragma unroll
            for (int g = 0; g < 2; ++g) {
                short8 o;
#pragma unroll
                for (int i = 0; i < 8; ++i)
                    o[i] = (short)f2bf(acc[g * 8 + i] * __builtin_amdgcn_rcpf(ls[g * 8 + i]));
                *(short8*)&agq[vd][th + g * 8] = o;
            }
        }
        __syncthreads();
        short8 Bp[2];
#pragma unroll
        for (int nt = 0; nt < 2; ++nt)
            Bp[nt] = *(const short8*)&Pbuf[w * 32 + nt * 16 + l15][tq * 32 + qd * 8];
#pragma unroll
        for (int mt = 0; mt < 8; ++mt) {
            const short8 Af = *(const short8*)&agq[mt * 16 + l15][qd * 8];
            oA[mt][0] = MFMA_BF16(Af, Bp[0], oA[mt][0]);
            oA[mt][1] = MFMA_BF16(Af, Bp[1], oA[mt][1]);
        }
        l1A[0] = MFMA_BF16(ones, Bp[0], l1A[0]);
        l1A[1] = MFMA_BF16(ones, Bp[1], l1A[1]);
    }

    // epilogue: divide by l1, pack 4 consecutive vd -> float4 coalesced store
#pragma unroll
    for (int nt = 0; nt < 2; ++nt) {
        const float inv = 1.0f / l1A[nt][0];
        const int n = n0 + w * 32 + nt * 16 + l15;
#pragma unroll
        for (int mt = 0; mt < 8; ++mt) {
            f32x4 ov;
#pragma unroll
            for (int r = 0; r < 4; ++r) ov[r] = oA[mt][nt][r] * inv;
            *(f32x4*)(oh + (size_t)n * D_ + mt * 16 + qd * 4) = ov;
        }
    }
}

extern "C" void kernel_launch(void* const* d_in, const int* in_sizes, int n_in,
                              void* d_out, int out_size, void* d_ws, size_t ws_size,
                              hipStream_t stream)
{
    (void)in_sizes; (void)n_in; (void)out_size; (void)ws_size;
    const float* q = (const float*)d_in[0];
    const float* a = (const float*)d_in[1];
    const float* k = (const float*)d_in[2];
    const float* v = (const float*)d_in[3];
    float* out  = (float*)d_out;
    float* accT = (float*)d_ws;                         // [BH][vd][t] fp32
    float* lsum = accT + (size_t)BH_ * D_ * D_;         // [BH][t] fp32
    const size_t zbytes = ((size_t)BH_ * D_ * D_ + (size_t)BH_ * D_) * sizeof(float);

    hipMemsetAsync(d_ws, 0, zbytes, stream);
    k1_agg<<<dim3(BH_ * 4), dim3(256), 0, stream>>>(a, k, v, accT, lsum);
    k2_out<<<dim3(BH_ * 16), dim3(256), 0, stream>>>(q, a, accT, lsum, out);
}